// Round 9
// baseline (191.881 us; speedup 1.0000x reference)
//
#include <hip/hip_runtime.h>
#include <math.h>

// ---------------------------------------------------------------------------
// bf16-MFMA pipeline v13:
//   flash_attn3 : rewritten on 32x32x16 MFMA (4 waves x 32 rows, Br=128,
//                 Bc=64, split-4, dbuf gl2lds). Halves LDS B-frag reads per
//                 flop (flash was LDS-throughput-bound: 22us floor at 16x16,
//                 ~14us at 32x32). P via XOR-swizzled [32][64] LDS. Opart/Ml
//                 format unchanged -> gemm_outf untouched.
//   wcast_all / gemm_qkv / gemm_outf : unchanged from v12.
// Layout: addr(tile,c,r,j) = ((tile*NC + c)*64 + r)*8 + j  (NC = K/8)
// ---------------------------------------------------------------------------

typedef __attribute__((ext_vector_type(8))) short bf16x8;
typedef __attribute__((ext_vector_type(4))) short bf16x4;
typedef __attribute__((ext_vector_type(4))) float f32x4;
typedef __attribute__((ext_vector_type(16))) float f32x16;

#define FA_SCL2 0.12751886525137387f   // 128^-0.5 * log2(e)

__device__ __forceinline__ unsigned short f2bf(float f) {
    __bf16 h = (__bf16)f;                       // native cvt (RNE)
    return __builtin_bit_cast(unsigned short, h);
}
__device__ __forceinline__ float bf2f(unsigned short h) {
    union { unsigned u; float f; } v; v.u = ((unsigned)h) << 16;
    return v.f;
}
__device__ __forceinline__ f32x4 mfma16(bf16x8 a, bf16x8 b, f32x4 c) {
    return __builtin_amdgcn_mfma_f32_16x16x32_bf16(a, b, c, 0, 0, 0);
}
__device__ __forceinline__ f32x16 mfma32(bf16x8 a, bf16x8 b, f32x16 c) {
    return __builtin_amdgcn_mfma_f32_32x32x16_bf16(a, b, c, 0, 0, 0);
}
__device__ __forceinline__ void gl2lds16(const void* g, void* l) {
    __builtin_amdgcn_global_load_lds(
        (const __attribute__((address_space(1))) unsigned int*)g,
        (__attribute__((address_space(3))) unsigned int*)l, 16, 0, 0);
}

// ---------------------------------------------------------------------------
// Merged weight cast. bx<192: w_qkv fp32[384][1024] -> Wfm frag-major.
// bx>=192: w_out fp32[1024][128] -> Wofm frag-major 64-row tiles.
// grid 256 x 256 thr.
// ---------------------------------------------------------------------------
__global__ __launch_bounds__(256)
void wcast_all(const float* __restrict__ Wq, const float* __restrict__ Wo,
               unsigned short* __restrict__ wfm, unsigned short* __restrict__ wofm)
{
    const int bx = blockIdx.x, tid = threadIdx.x;
    if (bx < 192) {
        const int idx = bx * 256 + tid;               // 49152 granules
        const int kc = idx & 127, r = idx >> 7;
        const float* g = Wq + (size_t)r * 1024 + kc * 8;
        float4 w0 = *(const float4*)g, w1 = *(const float4*)(g + 4);
        bf16x8 p;
        p[0] = (short)f2bf(w0.x); p[1] = (short)f2bf(w0.y);
        p[2] = (short)f2bf(w0.z); p[3] = (short)f2bf(w0.w);
        p[4] = (short)f2bf(w1.x); p[5] = (short)f2bf(w1.y);
        p[6] = (short)f2bf(w1.z); p[7] = (short)f2bf(w1.w);
        *(bf16x8*)&wfm[(size_t)(kc * 384 + r) * 8] = p;
    } else {
        const int idx = (bx - 192) * 256 + tid;       // 16384 granules
        const int c = idx & 15, rg = idx >> 4;        // rg in [0,1024)
        const float* g = Wo + (size_t)rg * 128 + c * 8;
        float4 w0 = *(const float4*)g, w1 = *(const float4*)(g + 4);
        bf16x8 p;
        p[0] = (short)f2bf(w0.x); p[1] = (short)f2bf(w0.y);
        p[2] = (short)f2bf(w0.z); p[3] = (short)f2bf(w0.w);
        p[4] = (short)f2bf(w1.x); p[5] = (short)f2bf(w1.y);
        p[6] = (short)f2bf(w1.z); p[7] = (short)f2bf(w1.w);
        *(bf16x8*)&wofm[((size_t)((rg >> 6) * 16 + c) * 64 + (rg & 63)) * 8] = p;
    }
}

// ---------------------------------------------------------------------------
// Fused QKV projection (unchanged v11). BM=64, BN=128 section, BK=64.
// grid 768 x 256 thr. V^T folded into epilogue.
// ---------------------------------------------------------------------------
__global__ __launch_bounds__(256, 3)
void gemm_qkv(const float* __restrict__ X, const unsigned short* __restrict__ Wfm,
              unsigned short* __restrict__ qfm, unsigned short* __restrict__ kfm,
              unsigned short* __restrict__ vfm)
{
    __shared__ unsigned short Asl[4096];         // 8 KB: granule(kc, row^kc)
    __shared__ unsigned short Bsl[2][8192];      // 2 x 16 KB: granule(kc, col)
    const int tid = threadIdx.x;
    const int wv = tid >> 6, lane = tid & 63;
    const int lm = lane & 15, quad = lane >> 4;
    const int mt = blockIdx.x & 255;             // M tile (64 rows) == Vfm tile
    const int nt = blockIdx.x >> 8;              // 0=Q, 1=K, 2=V
    const int mb = mt * 64, nb = nt * 128;
    const int wr = wv >> 1, wc = wv & 1;         // wave: rows wr*32, cols wc*64

    const int arow = tid >> 3, af8 = tid & 7;    // arow in [0,32)
    const float* gxr = X + (size_t)(mb + arow) * 1024 + af8 * 8;
    const int sg0 = (af8 * 64 + (arow ^ af8)) * 8;        // swizzled granule
    const int sg1 = sg0 + 32 * 8;                          // (arow+32)^af8

    f32x4 acc[2][4];
    #pragma unroll
    for (int i = 0; i < 2; ++i)
        #pragma unroll
        for (int j = 0; j < 4; ++j) acc[i][j] = f32x4{0.f, 0.f, 0.f, 0.f};

    auto loadA = [&](int it, float4& r0, float4& r1, float4& r2, float4& r3) {
        const float* g = gxr + it * 64;
        r0 = *(const float4*)g;
        r1 = *(const float4*)(g + 4);
        r2 = *(const float4*)(g + 32 * 1024);
        r3 = *(const float4*)(g + 32 * 1024 + 4);
    };
    auto stageA = [&](const float4& r0, const float4& r1,
                      const float4& r2, const float4& r3) {
        bf16x8 p0, p1;
        p0[0] = (short)f2bf(r0.x); p0[1] = (short)f2bf(r0.y);
        p0[2] = (short)f2bf(r0.z); p0[3] = (short)f2bf(r0.w);
        p0[4] = (short)f2bf(r1.x); p0[5] = (short)f2bf(r1.y);
        p0[6] = (short)f2bf(r1.z); p0[7] = (short)f2bf(r1.w);
        *(bf16x8*)&Asl[sg0] = p0;
        p1[0] = (short)f2bf(r2.x); p1[1] = (short)f2bf(r2.y);
        p1[2] = (short)f2bf(r2.z); p1[3] = (short)f2bf(r2.w);
        p1[4] = (short)f2bf(r3.x); p1[5] = (short)f2bf(r3.y);
        p1[6] = (short)f2bf(r3.z); p1[7] = (short)f2bf(r3.w);
        *(bf16x8*)&Asl[sg1] = p1;
    };
    auto issueB = [&](int it, int buf) {
        #pragma unroll
        for (int i = 0; i < 4; ++i) {
            const int p = wv * 4 + i;
            const int kc = p >> 1, colh = (p & 1) * 64;
            gl2lds16(Wfm + ((size_t)(it * 8 + kc) * 384 + nb + colh + lane) * 8,
                     &Bsl[buf][(kc * 128 + colh) * 8]);
        }
    };

    float4 a0, a1, a2, a3, b0, b1, b2, b3;
    loadA(0, a0, a1, a2, a3);
    issueB(0, 0);
    loadA(1, b0, b1, b2, b3);

    auto step = [&](const int i, float4& r0, float4& r1, float4& r2, float4& r3) {
        __builtin_amdgcn_s_barrier();            // B1: Asl + Bsl[(i+1)&1] free
        stageA(r0, r1, r2, r3);                  // implicit vmcnt wait for A(i)
        if (i < 15) issueB(i + 1, (i + 1) & 1);
        if (i < 14) {
            loadA(i + 2, r0, r1, r2, r3);        // 2-iter slack
            asm volatile("s_waitcnt vmcnt(12) lgkmcnt(0)" ::: "memory"); // B(i) done
        } else if (i == 14) {
            asm volatile("s_waitcnt vmcnt(8) lgkmcnt(0)" ::: "memory");
        } else {
            asm volatile("s_waitcnt vmcnt(0) lgkmcnt(0)" ::: "memory");
        }
        __builtin_amdgcn_s_barrier();            // B2: tile i ready
        const unsigned short* Bc = Bsl[i & 1];
        bf16x8 af[2][2], bfr[2][4];
        #pragma unroll
        for (int s = 0; s < 2; ++s) {
            const int kc = s * 4 + quad;
            #pragma unroll
            for (int ii = 0; ii < 2; ++ii)
                af[s][ii] = *(const bf16x8*)
                    &Asl[(kc * 64 + ((wr * 32 + ii * 16 + lm) ^ kc)) * 8];
            #pragma unroll
            for (int j = 0; j < 4; ++j)
                bfr[s][j] = *(const bf16x8*)&Bc[(kc * 128 + wc * 64 + j * 16 + lm) * 8];
        }
        #pragma unroll
        for (int s = 0; s < 2; ++s)
            #pragma unroll
            for (int ii = 0; ii < 2; ++ii)
                #pragma unroll
                for (int j = 0; j < 4; ++j)
                    acc[ii][j] = mfma16(af[s][ii], bfr[s][j], acc[ii][j]);
    };

    for (int p = 0; p < 8; ++p) {
        step(2 * p,     a0, a1, a2, a3);
        step(2 * p + 1, b0, b1, b2, b3);
    }

    if (nt == 2) {
        // V: transpose in LDS (T[d][k], stride 72; aliases dead Bsl) and
        // write Vfm tile mt directly.
        unsigned short* T = &Bsl[0][0];          // 128*72*2 = 18.4 KB < 32 KB
        __syncthreads();
        #pragma unroll
        for (int ii = 0; ii < 2; ++ii)
            #pragma unroll
            for (int j = 0; j < 4; ++j) {
                const int d = wc * 64 + j * 16 + lm;
                const int k0 = wr * 32 + ii * 16 + quad * 4;
                bf16x4 v;
                v[0] = (short)f2bf(acc[ii][j][0]);
                v[1] = (short)f2bf(acc[ii][j][1]);
                v[2] = (short)f2bf(acc[ii][j][2]);
                v[3] = (short)f2bf(acc[ii][j][3]);
                *(bf16x4*)&T[d * 72 + k0] = v;
            }
        __syncthreads();
        unsigned short* dst = vfm + (size_t)mt * 8192;
        #pragma unroll
        for (int t = 0; t < 4; ++t) {
            const int g = tid + t * 256;         // granule: d = g&127, c = g>>7
            const int d = g & 127, c = g >> 7;
            bf16x8 x = *(const bf16x8*)&T[d * 72 + c * 8];
            *(bf16x8*)(dst + (size_t)(c * 128 + d) * 8) = x;   // coalesced
        }
    } else {                                    // Q (scaled) / K: frag-major
        unsigned short* dst = nt ? kfm : qfm;
        const float scl = nt ? 1.f : FA_SCL2;
        #pragma unroll
        for (int ii = 0; ii < 2; ++ii)
            #pragma unroll
            for (int j = 0; j < 4; ++j) {
                const int ncol = wc * 64 + j * 16 + lm;
                const size_t cb = ((size_t)mt * 16 + (ncol >> 3)) * 512 + (ncol & 7);
                #pragma unroll
                for (int r = 0; r < 4; ++r)
                    dst[cb + (size_t)(wr * 32 + ii * 16 + quad * 4 + r) * 8]
                        = f2bf(acc[ii][j][r] * scl);
            }
    }
}

// ---------------------------------------------------------------------------
// Flash attention v13: 256 thr (4 waves x 32 rows), Br=128, Bc=64, 32x32x16
// MFMA. KV-split x4, balanced mapping, dbuf gl2lds (vmcnt(8)), defer-max,
// ones-col MFMA row-sum. P in XOR-swizzled wave-private LDS [32][64].
// LDS 80 KB -> 2 blocks/CU. Opart/Ml format identical to v12.
// ---------------------------------------------------------------------------
__global__ __launch_bounds__(256)
void flash_attn3(const unsigned short* __restrict__ Qfm, const unsigned short* __restrict__ Kfm,
                 const unsigned short* __restrict__ Vfm,
                 unsigned short* __restrict__ Opart, float* __restrict__ Ml)
{
    __shared__ unsigned short Klds[2][8192];    // 2 x 16 KB (Q stages both)
    __shared__ unsigned short Vlds[2][8192];    // 2 x 16 KB
    __shared__ unsigned short Plds[4][2048];    // per-wave P [32][64] swizzled

    const int tid = threadIdx.x;
    const int wv = tid >> 6, lane = tid & 63;
    const int l31 = lane & 31, lh = lane >> 5;

    const int bx = blockIdx.x;
    const int xcd = bx & 7;
    const int b   = xcd >> 1;                    // batch on XCD pair {2b,2b+1}
    const int r   = (bx >> 3) * 2 + (xcd & 1);   // [0,128) per batch
    const int sp  = r & 3;
    const int Qi  = (r < 64) ? (16 + (r >> 2)) : (15 - ((r - 64) >> 2));
    const int n   = 2 * Qi + 2;                  // key tiles for this Q-block
    const int cnt = (n >> 2) + ((sp < (n & 3)) ? 1 : 0);
    const int ktb = sp * (n >> 2) + ((sp < (n & 3)) ? sp : (n & 3));
    const int kte = ktb + cnt;
    const int qt0 = 2 * Qi;
    const int qtw = qt0 + (wv >> 1);             // wave's 64-row q-tile
    const int rh  = (wv & 1) * 32;               // row-half within that tile

    const size_t ob0 = (size_t)((b * 64 + qt0) * 4 + sp) * 8192;
    const size_t ob1 = ob0 + 4 * 8192;
    const int mlb0 = ((b * 64 + qt0) * 4 + sp) * 128, mlb1 = mlb0 + 512;

    if (cnt == 0) {                      // neutral partial (both tiles)
        bf16x8 z = {0, 0, 0, 0, 0, 0, 0, 0};
        #pragma unroll
        for (int t = 0; t < 4; ++t) {
            *(bf16x8*)&Opart[ob0 + (size_t)(tid + t * 256) * 8] = z;
            *(bf16x8*)&Opart[ob1 + (size_t)(tid + t * 256) * 8] = z;
        }
        if (tid < 64) { Ml[mlb0 + tid] = -INFINITY; Ml[mlb1 + tid] = -INFINITY; }
        else if (tid < 128) { Ml[mlb0 + tid] = 0.f; Ml[mlb1 + tid] = 0.f; }
        return;
    }

    // stage both Q tiles (32 KB) into Klds[0..1] (contiguous), frags to regs
    {
        const size_t qb = (size_t)(b * 64 + qt0) * 8192;
        #pragma unroll
        for (int i = 0; i < 8; ++i) {
            const int p = wv * 8 + i;            // 32 pieces of 1 KB
            gl2lds16(Qfm + qb + (size_t)p * 512 + lane * 8, &Klds[0][0] + p * 512);
        }
    }
    __syncthreads();
    bf16x8 qf[8];                                // 32 rows x 128 k, A-frags
    {
        const unsigned short* Qt = &Klds[0][0] + (wv >> 1) * 8192;
        #pragma unroll
        for (int m = 0; m < 8; ++m)
            qf[m] = *(const bf16x8*)&Qt[((m * 2 + lh) * 64 + rh + l31) * 8];
    }
    asm volatile("s_waitcnt lgkmcnt(0)" ::: "memory");   // qf secured
    __builtin_amdgcn_s_barrier();

    // prologue: first K/V tile -> buf 0 (overwrites Q: safe)
    {
        const size_t kb = (size_t)(b * 64 + ktb) * 8192;
        #pragma unroll
        for (int i = 0; i < 4; ++i) {
            const int pc = wv * 4 + i;           // 16 pieces each
            gl2lds16(Kfm + kb + pc * 512 + lane * 8, &Klds[0][pc * 512]);
            gl2lds16(Vfm + kb + pc * 512 + lane * 8, &Vlds[0][pc * 512]);
        }
    }

    f32x16 oacc[4];                              // 32 rows x 128 d
    #pragma unroll
    for (int dc = 0; dc < 4; ++dc)
        #pragma unroll
        for (int e = 0; e < 16; ++e) oacc[dc][e] = 0.f;
    f32x16 m16, lacc;
    #pragma unroll
    for (int e = 0; e < 16; ++e) { m16[e] = -INFINITY; lacc[e] = 0.f; }
    unsigned short* Pw = Plds[wv];
    const short ONE = (short)0x3F80;             // bf16 1.0
    const bf16x8 ONESB = {ONE, ONE, ONE, ONE, ONE, ONE, ONE, ONE};
    const int swzr = (l31 & 7) << 3;             // read-side P swizzle

    for (int kt = ktb; kt < kte; ++kt) {
        const int cu = (kt - ktb) & 1;
        __builtin_amdgcn_s_barrier();    // B1: buf[cu^1] free to overwrite
        if (kt + 1 < kte) {
            const size_t kb = (size_t)(b * 64 + kt + 1) * 8192;
            #pragma unroll
            for (int i = 0; i < 4; ++i) {
                const int pc = wv * 4 + i;
                gl2lds16(Kfm + kb + pc * 512 + lane * 8, &Klds[cu ^ 1][pc * 512]);
                gl2lds16(Vfm + kb + pc * 512 + lane * 8, &Vlds[cu ^ 1][pc * 512]);
            }
            asm volatile("s_waitcnt vmcnt(8)" ::: "memory");  // tile kt done
        } else {
            asm volatile("s_waitcnt vmcnt(0)" ::: "memory");
        }
        __builtin_amdgcn_s_barrier();    // B2: buf[cu] ready
        if (kt > qtw) continue;          // wave's rows fully masked this tile

        const unsigned short* Kc = &Klds[cu][0];
        const unsigned short* Vc = &Vlds[cu][0];

        // S = Q K^T : 32 rows x 64 keys (two 32x32 outputs), Q pre-scaled
        f32x16 s0, s1;
        #pragma unroll
        for (int e = 0; e < 16; ++e) { s0[e] = 0.f; s1[e] = 0.f; }
        __builtin_amdgcn_s_setprio(1);
        #pragma unroll
        for (int m = 0; m < 8; ++m) {
            bf16x8 kf0 = *(const bf16x8*)&Kc[((m * 2 + lh) * 64 + l31) * 8];
            bf16x8 kf1 = *(const bf16x8*)&Kc[((m * 2 + lh) * 64 + 32 + l31) * 8];
            s0 = mfma32(qf[m], kf0, s0);
            s1 = mfma32(qf[m], kf1, s1);
        }
        __builtin_amdgcn_s_setprio(0);
        if (kt == qtw) {                 // diagonal tile: mask key > row
            #pragma unroll
            for (int reg = 0; reg < 16; ++reg) {
                const int rowt = rh + (reg & 3) + 8 * (reg >> 2) + 4 * lh;
                if (l31 > rowt)      s0[reg] = -INFINITY;
                if (32 + l31 > rowt) s1[reg] = -INFINITY;
            }
        }
        // defer-max online softmax (base 2); rows = 16 regs per lane
        float dm = -INFINITY;
        f32x16 pmax;
        #pragma unroll
        for (int e = 0; e < 16; ++e) {
            pmax[e] = fmaxf(s0[e], s1[e]);
            dm = fmaxf(dm, pmax[e] - m16[e]);
        }
        if (!__all(dm <= 8.f)) {
            f32x16 rmax = pmax;
            #pragma unroll
            for (int d = 1; d < 32; d <<= 1)
                #pragma unroll
                for (int e = 0; e < 16; ++e)
                    rmax[e] = fmaxf(rmax[e], __shfl_xor(rmax[e], d));
            f32x16 alpha;
            #pragma unroll
            for (int e = 0; e < 16; ++e) {
                const float mn = fmaxf(m16[e], rmax[e]);   // finite (diag row)
                alpha[e] = __builtin_amdgcn_exp2f(m16[e] - mn);
                m16[e] = mn;
            }
            #pragma unroll
            for (int dc = 0; dc < 4; ++dc) oacc[dc] *= alpha;
            lacc *= alpha;
        }
        #pragma unroll
        for (int e = 0; e < 16; ++e) {
            s0[e] = __builtin_amdgcn_exp2f(s0[e] - m16[e]);
            s1[e] = __builtin_amdgcn_exp2f(s1[e] - m16[e]);
        }
        // P -> wave-private LDS [32][64], key ^= (row&7)<<3 swizzle
        #pragma unroll
        for (int reg = 0; reg < 16; ++reg) {
            const int R = (reg & 3) + 8 * (reg >> 2) + 4 * lh;
            const int sw = (R & 7) << 3;
            Pw[R * 64 + (l31 ^ sw)]        = f2bf(s0[reg]);
            Pw[R * 64 + ((32 + l31) ^ sw)] = f2bf(s1[reg]);
        }
        // O += P V ; l += P 1  (row-sum via ones-column MFMA)
        __builtin_amdgcn_s_setprio(1);
        #pragma unroll
        for (int s4 = 0; s4 < 4; ++s4) {
            const int k0 = s4 * 16 + lh * 8;
            bf16x8 pf = *(const bf16x8*)&Pw[l31 * 64 + (k0 ^ swzr)];
            lacc = mfma32(pf, ONESB, lacc);
            #pragma unroll
            for (int dc = 0; dc < 4; ++dc) {
                bf16x8 vf = *(const bf16x8*)&Vc[((s4 * 2 + lh) * 128 + dc * 32 + l31) * 8];
                oacc[dc] = mfma32(pf, vf, oacc[dc]);
            }
        }
        __builtin_amdgcn_s_setprio(0);
    }

    // epilogue: wave's 32 rows (tile qtw, half rh) -> Opart granules + Ml
    const size_t obw = (size_t)((b * 64 + qtw) * 4 + sp) * 8192;
    const int mlw = ((b * 64 + qtw) * 4 + sp) * 128;
    #pragma unroll
    for (int dc = 0; dc < 4; ++dc) {
        const int d = dc * 32 + l31;
        const size_t cb = obw + (size_t)(d >> 3) * 512 + (d & 7);
        #pragma unroll
        for (int reg = 0; reg < 16; ++reg) {
            const int row64 = rh + (reg & 3) + 8 * (reg >> 2) + 4 * lh;
            Opart[cb + (size_t)row64 * 8] = f2bf(oacc[dc][reg]);
        }
    }
    if (l31 == 0)
        #pragma unroll
        for (int reg = 0; reg < 16; ++reg) {
            const int row64 = rh + (reg & 3) + 8 * (reg >> 2) + 4 * lh;
            Ml[mlw + row64] = m16[reg];
            Ml[mlw + 64 + row64] = lacc[reg];
        }
}

// ---------------------------------------------------------------------------
// Output projection (unchanged v12): combine(4 splits) + GEMM + bias.
// grid (256 aq, 2 nh) x 512 thr. LDS: A 16 KB + W dbuf 2x32 KB = 80 KB.
// ---------------------------------------------------------------------------
__global__ __launch_bounds__(512, 2)
void gemm_outf(const unsigned short* __restrict__ Opart, const float* __restrict__ Ml,
               const unsigned short* __restrict__ Wofm, const float* __restrict__ bias,
               float* __restrict__ out)
{
    __shared__ unsigned short Asl[8192];        // 16 KB combined A (16 kc x 64 rows)
    __shared__ unsigned short Wl[2][16384];     // 2 x 32 KB
    const int tid = threadIdx.x;
    const int wv = tid >> 6, lane = tid & 63;
    const int lm = lane & 15, quad = lane >> 4;
    const int aq = blockIdx.x;                  // 0..255 : (b*64 + qt)
    const int nt0 = blockIdx.y * 4;             // n-tile base (4 tiles of 128)
    const size_t pbase = (size_t)aq * 4 * 8192;
    const int mlb = aq * 4 * 128;

    auto issueW = [&](int nt, int buf) {
        #pragma unroll
        for (int i = 0; i < 4; ++i) {
            const int p = wv * 4 + i;           // 0..31 pieces of 1 KB
            gl2lds16(Wofm + (size_t)((nt * 2 + (p >> 4)) * 16 + (p & 15)) * 512 + lane * 8,
                     &Wl[buf][p * 512]);
        }
    };
    issueW(nt0, 0);                             // W(nt0) in flight under combine

    // ---- Phase 1: combine 4 splits into Asl ----
    {
        const int r = tid & 63;
        float m[4], l[4];
        #pragma unroll
        for (int s = 0; s < 4; ++s) {
            m[s] = Ml[mlb + s * 128 + r];
            l[s] = Ml[mlb + s * 128 + 64 + r];
        }
        const float M = fmaxf(fmaxf(m[0], m[1]), fmaxf(m[2], m[3]));
        float a[4], den = 0.f;
        #pragma unroll
        for (int s = 0; s < 4; ++s) {
            a[s] = __builtin_amdgcn_exp2f(m[s] - M);
            den += a[s] * l[s];
        }
        const float rsc = 1.f / den;
        #pragma unroll
        for (int h = 0; h < 2; ++h) {
            const int g = tid + h * 512;
            float acc8[8] = {};
            #pragma unroll
            for (int s = 0; s < 4; ++s) {
                bf16x8 x = *(const bf16x8*)&Opart[pbase + (size_t)s * 8192 + (size_t)g * 8];
                #pragma unroll
                for (int e = 0; e < 8; ++e) acc8[e] += a[s] * bf2f((unsigned short)x[e]);
            }
            bf16x8 o;
            #pragma unroll
            for (int e = 0; e < 8; ++e) o[e] = f2bf(acc8[e] * rsc);
            *(bf16x8*)&Asl[g * 8] = o;
        }
    }
    __syncthreads();                            // Asl ready

    // ---- Phase 2: 4 N-tiles, W double-buffered ----
    const int rw4 = (wv & 3) * 16;              // wave rows
    const int tl  = wv >> 2;                    // wave col-half (0/1)
    bf16x8 af[4];
    #pragma unroll
    for (int kt = 0; kt < 4; ++kt)
        af[kt] = *(const bf16x8*)&Asl[((kt * 4 + quad) * 64 + rw4 + lm) * 8];

    for (int it = 0; it < 4; ++it) {
        const int nt = nt0 + it;
        const int buf = it & 1;
        if (it < 3) {
            asm volatile("s_waitcnt vmcnt(4)" ::: "memory");   // W(nt) done
        } else {
            asm volatile("s_waitcnt vmcnt(0)" ::: "memory");
        }
        __builtin_amdgcn_s_barrier();           // W(nt) visible; buf^1 free
        if (it < 3) issueW(nt + 1, buf ^ 1);

        f32x4 acc[4];
        #pragma unroll
        for (int j = 0; j < 4; ++j) acc[j] = f32x4{0.f, 0.f, 0.f, 0.f};
        #pragma unroll
        for (int kt = 0; kt < 4; ++kt)
            #pragma unroll
            for (int j = 0; j < 4; ++j) {
                bf16x8 bfr = *(const bf16x8*)
                    &Wl[buf][((tl * 16 + kt * 4 + quad) * 64 + j * 16 + lm) * 8];
                acc[j] = mfma16(af[kt], bfr, acc[j]);
            }
        #pragma unroll
        for (int j = 0; j < 4; ++j) {
            const int col = nt * 128 + tl * 64 + j * 16 + lm;
            const float bv = bias[col];
            #pragma unroll
            for (int rr = 0; rr < 4; ++rr) {
                const int m = aq * 64 + rw4 + quad * 4 + rr;
                out[(size_t)m * 1024 + col] = acc[j][rr] + bv;
            }
        }
        __builtin_amdgcn_s_barrier();           // done reading Wl[buf]
    }
}

// ---------------------------------------------------------------------------
extern "C" void kernel_launch(void* const* d_in, const int* in_sizes, int n_in,
                              void* d_out, int out_size, void* d_ws, size_t ws_size,
                              hipStream_t stream)
{
    (void)in_sizes; (void)n_in; (void)out_size; (void)ws_size;
    const float* x     = (const float*)d_in[0];
    const float* w_qkv = (const float*)d_in[1];
    const float* w_out = (const float*)d_in[2];
    const float* b_out = (const float*)d_in[3];
    float* out = (float*)d_out;
    unsigned short* ws = (unsigned short*)d_ws;

    const size_t NE = (size_t)16384 * 128;          // 2 097 152
    unsigned short* qfm = ws;                        // 4 MB
    unsigned short* kfm = ws + NE;                   // 4 MB
    unsigned short* wofm = ws + 2 * NE;              // w_out bf16 frag-major
    unsigned short* vfm = ws + 3 * NE;               // 4 MB
    unsigned short* op  = ws + 4 * NE;               // Opart 16.8 MB
    float*          ml  = (float*)(ws + 8 * NE);     // 0.5 MB
    unsigned short* wfm = op;                        // alias: dead before flash

    hipLaunchKernelGGL(wcast_all,   dim3(256),      dim3(256), 0, stream, w_qkv, w_out, wfm, wofm);
    hipLaunchKernelGGL(gemm_qkv,    dim3(768),      dim3(256), 0, stream, x, wfm, qfm, kfm, vfm);
    hipLaunchKernelGGL(flash_attn3, dim3(512),      dim3(256), 0, stream, qfm, kfm, vfm, op, ml);
    hipLaunchKernelGGL(gemm_outf,   dim3(256, 2),   dim3(512), 0, stream, op, ml, wofm, b_out, out);
}

// Round 10
// 177.451 us; speedup vs baseline: 1.0813x; 1.0813x over previous
//
#include <hip/hip_runtime.h>
#include <math.h>

// ---------------------------------------------------------------------------
// bf16-MFMA pipeline v14:
//   flash_attn3 : REVERTED to v12 (16x16 MFMA, 512 thr, 16 waves/CU). The
//                 v13 32x32 rewrite halved occupancy (8 waves/CU) and
//                 serialized MFMA chains -> 36us -> 73.7us. Reverted.
//   gemm_outf   : grid flattened to 1D so the 2 blocks sharing an aq-tile
//                 land on the same XCD (Opart/Ml re-reads become L2 hits).
//   wcast_all / gemm_qkv : unchanged from v12.
// Layout: addr(tile,c,r,j) = ((tile*NC + c)*64 + r)*8 + j  (NC = K/8)
// ---------------------------------------------------------------------------

typedef __attribute__((ext_vector_type(8))) short bf16x8;
typedef __attribute__((ext_vector_type(4))) short bf16x4;
typedef __attribute__((ext_vector_type(4))) float f32x4;

#define FA_SCL2 0.12751886525137387f   // 128^-0.5 * log2(e)

__device__ __forceinline__ unsigned short f2bf(float f) {
    __bf16 h = (__bf16)f;                       // native cvt (RNE)
    return __builtin_bit_cast(unsigned short, h);
}
__device__ __forceinline__ float bf2f(unsigned short h) {
    union { unsigned u; float f; } v; v.u = ((unsigned)h) << 16;
    return v.f;
}
__device__ __forceinline__ f32x4 mfma16(bf16x8 a, bf16x8 b, f32x4 c) {
    return __builtin_amdgcn_mfma_f32_16x16x32_bf16(a, b, c, 0, 0, 0);
}
__device__ __forceinline__ void gl2lds16(const void* g, void* l) {
    __builtin_amdgcn_global_load_lds(
        (const __attribute__((address_space(1))) unsigned int*)g,
        (__attribute__((address_space(3))) unsigned int*)l, 16, 0, 0);
}
__device__ __forceinline__ f32x4 vmax4(f32x4 a, f32x4 b) {
    return f32x4{fmaxf(a[0], b[0]), fmaxf(a[1], b[1]),
                 fmaxf(a[2], b[2]), fmaxf(a[3], b[3])};
}

// ---------------------------------------------------------------------------
// Merged weight cast. bx<192: w_qkv fp32[384][1024] -> Wfm frag-major.
// bx>=192: w_out fp32[1024][128] -> Wofm frag-major 64-row tiles.
// grid 256 x 256 thr.
// ---------------------------------------------------------------------------
__global__ __launch_bounds__(256)
void wcast_all(const float* __restrict__ Wq, const float* __restrict__ Wo,
               unsigned short* __restrict__ wfm, unsigned short* __restrict__ wofm)
{
    const int bx = blockIdx.x, tid = threadIdx.x;
    if (bx < 192) {
        const int idx = bx * 256 + tid;               // 49152 granules
        const int kc = idx & 127, r = idx >> 7;
        const float* g = Wq + (size_t)r * 1024 + kc * 8;
        float4 w0 = *(const float4*)g, w1 = *(const float4*)(g + 4);
        bf16x8 p;
        p[0] = (short)f2bf(w0.x); p[1] = (short)f2bf(w0.y);
        p[2] = (short)f2bf(w0.z); p[3] = (short)f2bf(w0.w);
        p[4] = (short)f2bf(w1.x); p[5] = (short)f2bf(w1.y);
        p[6] = (short)f2bf(w1.z); p[7] = (short)f2bf(w1.w);
        *(bf16x8*)&wfm[(size_t)(kc * 384 + r) * 8] = p;
    } else {
        const int idx = (bx - 192) * 256 + tid;       // 16384 granules
        const int c = idx & 15, rg = idx >> 4;        // rg in [0,1024)
        const float* g = Wo + (size_t)rg * 128 + c * 8;
        float4 w0 = *(const float4*)g, w1 = *(const float4*)(g + 4);
        bf16x8 p;
        p[0] = (short)f2bf(w0.x); p[1] = (short)f2bf(w0.y);
        p[2] = (short)f2bf(w0.z); p[3] = (short)f2bf(w0.w);
        p[4] = (short)f2bf(w1.x); p[5] = (short)f2bf(w1.y);
        p[6] = (short)f2bf(w1.z); p[7] = (short)f2bf(w1.w);
        *(bf16x8*)&wofm[((size_t)((rg >> 6) * 16 + c) * 64 + (rg & 63)) * 8] = p;
    }
}

// ---------------------------------------------------------------------------
// Fused QKV projection (unchanged). BM=64, BN=128 section, BK=64.
// grid 768 x 256 thr. V^T folded into epilogue.
// ---------------------------------------------------------------------------
__global__ __launch_bounds__(256, 3)
void gemm_qkv(const float* __restrict__ X, const unsigned short* __restrict__ Wfm,
              unsigned short* __restrict__ qfm, unsigned short* __restrict__ kfm,
              unsigned short* __restrict__ vfm)
{
    __shared__ unsigned short Asl[4096];         // 8 KB: granule(kc, row^kc)
    __shared__ unsigned short Bsl[2][8192];      // 2 x 16 KB: granule(kc, col)
    const int tid = threadIdx.x;
    const int wv = tid >> 6, lane = tid & 63;
    const int lm = lane & 15, quad = lane >> 4;
    const int mt = blockIdx.x & 255;             // M tile (64 rows) == Vfm tile
    const int nt = blockIdx.x >> 8;              // 0=Q, 1=K, 2=V
    const int mb = mt * 64, nb = nt * 128;
    const int wr = wv >> 1, wc = wv & 1;         // wave: rows wr*32, cols wc*64

    const int arow = tid >> 3, af8 = tid & 7;    // arow in [0,32)
    const float* gxr = X + (size_t)(mb + arow) * 1024 + af8 * 8;
    const int sg0 = (af8 * 64 + (arow ^ af8)) * 8;        // swizzled granule
    const int sg1 = sg0 + 32 * 8;                          // (arow+32)^af8

    f32x4 acc[2][4];
    #pragma unroll
    for (int i = 0; i < 2; ++i)
        #pragma unroll
        for (int j = 0; j < 4; ++j) acc[i][j] = f32x4{0.f, 0.f, 0.f, 0.f};

    auto loadA = [&](int it, float4& r0, float4& r1, float4& r2, float4& r3) {
        const float* g = gxr + it * 64;
        r0 = *(const float4*)g;
        r1 = *(const float4*)(g + 4);
        r2 = *(const float4*)(g + 32 * 1024);
        r3 = *(const float4*)(g + 32 * 1024 + 4);
    };
    auto stageA = [&](const float4& r0, const float4& r1,
                      const float4& r2, const float4& r3) {
        bf16x8 p0, p1;
        p0[0] = (short)f2bf(r0.x); p0[1] = (short)f2bf(r0.y);
        p0[2] = (short)f2bf(r0.z); p0[3] = (short)f2bf(r0.w);
        p0[4] = (short)f2bf(r1.x); p0[5] = (short)f2bf(r1.y);
        p0[6] = (short)f2bf(r1.z); p0[7] = (short)f2bf(r1.w);
        *(bf16x8*)&Asl[sg0] = p0;
        p1[0] = (short)f2bf(r2.x); p1[1] = (short)f2bf(r2.y);
        p1[2] = (short)f2bf(r2.z); p1[3] = (short)f2bf(r2.w);
        p1[4] = (short)f2bf(r3.x); p1[5] = (short)f2bf(r3.y);
        p1[6] = (short)f2bf(r3.z); p1[7] = (short)f2bf(r3.w);
        *(bf16x8*)&Asl[sg1] = p1;
    };
    auto issueB = [&](int it, int buf) {
        #pragma unroll
        for (int i = 0; i < 4; ++i) {
            const int p = wv * 4 + i;
            const int kc = p >> 1, colh = (p & 1) * 64;
            gl2lds16(Wfm + ((size_t)(it * 8 + kc) * 384 + nb + colh + lane) * 8,
                     &Bsl[buf][(kc * 128 + colh) * 8]);
        }
    };

    float4 a0, a1, a2, a3, b0, b1, b2, b3;
    loadA(0, a0, a1, a2, a3);
    issueB(0, 0);
    loadA(1, b0, b1, b2, b3);

    auto step = [&](const int i, float4& r0, float4& r1, float4& r2, float4& r3) {
        __builtin_amdgcn_s_barrier();            // B1: Asl + Bsl[(i+1)&1] free
        stageA(r0, r1, r2, r3);                  // implicit vmcnt wait for A(i)
        if (i < 15) issueB(i + 1, (i + 1) & 1);
        if (i < 14) {
            loadA(i + 2, r0, r1, r2, r3);        // 2-iter slack
            asm volatile("s_waitcnt vmcnt(12) lgkmcnt(0)" ::: "memory"); // B(i) done
        } else if (i == 14) {
            asm volatile("s_waitcnt vmcnt(8) lgkmcnt(0)" ::: "memory");
        } else {
            asm volatile("s_waitcnt vmcnt(0) lgkmcnt(0)" ::: "memory");
        }
        __builtin_amdgcn_s_barrier();            // B2: tile i ready
        const unsigned short* Bc = Bsl[i & 1];
        bf16x8 af[2][2], bfr[2][4];
        #pragma unroll
        for (int s = 0; s < 2; ++s) {
            const int kc = s * 4 + quad;
            #pragma unroll
            for (int ii = 0; ii < 2; ++ii)
                af[s][ii] = *(const bf16x8*)
                    &Asl[(kc * 64 + ((wr * 32 + ii * 16 + lm) ^ kc)) * 8];
            #pragma unroll
            for (int j = 0; j < 4; ++j)
                bfr[s][j] = *(const bf16x8*)&Bc[(kc * 128 + wc * 64 + j * 16 + lm) * 8];
        }
        #pragma unroll
        for (int s = 0; s < 2; ++s)
            #pragma unroll
            for (int ii = 0; ii < 2; ++ii)
                #pragma unroll
                for (int j = 0; j < 4; ++j)
                    acc[ii][j] = mfma16(af[s][ii], bfr[s][j], acc[ii][j]);
    };

    for (int p = 0; p < 8; ++p) {
        step(2 * p,     a0, a1, a2, a3);
        step(2 * p + 1, b0, b1, b2, b3);
    }

    if (nt == 2) {
        // V: transpose in LDS (T[d][k], stride 72; aliases dead Bsl) and
        // write Vfm tile mt directly.
        unsigned short* T = &Bsl[0][0];          // 128*72*2 = 18.4 KB < 32 KB
        __syncthreads();
        #pragma unroll
        for (int ii = 0; ii < 2; ++ii)
            #pragma unroll
            for (int j = 0; j < 4; ++j) {
                const int d = wc * 64 + j * 16 + lm;
                const int k0 = wr * 32 + ii * 16 + quad * 4;
                bf16x4 v;
                v[0] = (short)f2bf(acc[ii][j][0]);
                v[1] = (short)f2bf(acc[ii][j][1]);
                v[2] = (short)f2bf(acc[ii][j][2]);
                v[3] = (short)f2bf(acc[ii][j][3]);
                *(bf16x4*)&T[d * 72 + k0] = v;
            }
        __syncthreads();
        unsigned short* dst = vfm + (size_t)mt * 8192;
        #pragma unroll
        for (int t = 0; t < 4; ++t) {
            const int g = tid + t * 256;         // granule: d = g&127, c = g>>7
            const int d = g & 127, c = g >> 7;
            bf16x8 x = *(const bf16x8*)&T[d * 72 + c * 8];
            *(bf16x8*)(dst + (size_t)(c * 128 + d) * 8) = x;   // coalesced
        }
    } else {                                    // Q (scaled) / K: frag-major
        unsigned short* dst = nt ? kfm : qfm;
        const float scl = nt ? 1.f : FA_SCL2;
        #pragma unroll
        for (int ii = 0; ii < 2; ++ii)
            #pragma unroll
            for (int j = 0; j < 4; ++j) {
                const int ncol = wc * 64 + j * 16 + lm;
                const size_t cb = ((size_t)mt * 16 + (ncol >> 3)) * 512 + (ncol & 7);
                #pragma unroll
                for (int r = 0; r < 4; ++r)
                    dst[cb + (size_t)(wr * 32 + ii * 16 + quad * 4 + r) * 8]
                        = f2bf(acc[ii][j][r] * scl);
            }
    }
}

// ---------------------------------------------------------------------------
// Flash attention (v12 revert): 512 thr, Br=128, balanced, ones-col MFMA,
// defer-max, masked-tile skip. launch_bounds(512,4).
// ---------------------------------------------------------------------------
__global__ __launch_bounds__(512, 4)
void flash_attn3(const unsigned short* __restrict__ Qfm, const unsigned short* __restrict__ Kfm,
                 const unsigned short* __restrict__ Vfm,
                 unsigned short* __restrict__ Opart, float* __restrict__ Ml)
{
    __shared__ unsigned short Klds[2][8192];    // 2 x 16 KB (Q stages both)
    __shared__ unsigned short Vlds[2][8192];    // 2 x 16 KB
    __shared__ unsigned short Plds[8][1024];    // per-wave P (A-frag), 16 KB

    const int tid = threadIdx.x;
    const int wv = tid >> 6, lane = tid & 63;
    const int lm = lane & 15, quad = lane >> 4;

    const int bx = blockIdx.x;
    const int xcd = bx & 7;
    const int b   = xcd >> 1;                    // batch on XCD pair {2b,2b+1}
    const int r   = (bx >> 3) * 2 + (xcd & 1);   // [0,128) per batch
    const int sp  = r & 3;
    const int Qi  = (r < 64) ? (16 + (r >> 2)) : (15 - ((r - 64) >> 2));
    const int n   = 2 * Qi + 2;                  // key tiles for this Q-block
    const int cnt = (n >> 2) + ((sp < (n & 3)) ? 1 : 0);
    const int ktb = sp * (n >> 2) + ((sp < (n & 3)) ? sp : (n & 3));
    const int kte = ktb + cnt;
    const int qtw = 2 * Qi + (wv >> 2);          // wave's 64-row q-tile
    const int rw  = (wv & 3) * 16;               // wave's rows inside the tile

    const int qt0 = 2 * Qi;
    const size_t ob0 = (size_t)((b * 64 + qt0) * 4 + sp) * 8192;
    const size_t ob1 = ob0 + 4 * 8192;
    const int mlb0 = ((b * 64 + qt0) * 4 + sp) * 128, mlb1 = mlb0 + 512;

    if (cnt == 0) {                      // neutral partial (both tiles)
        bf16x8 z = {0, 0, 0, 0, 0, 0, 0, 0};
        #pragma unroll
        for (int t = 0; t < 2; ++t) {
            *(bf16x8*)&Opart[ob0 + (size_t)(tid + t * 512) * 8] = z;
            *(bf16x8*)&Opart[ob1 + (size_t)(tid + t * 512) * 8] = z;
        }
        if (tid < 64) { Ml[mlb0 + tid] = -INFINITY; Ml[mlb1 + tid] = -INFINITY; }
        else if (tid < 128) { Ml[mlb0 + tid] = 0.f; Ml[mlb1 + tid] = 0.f; }
        return;
    }

    // stage both Q tiles (32 KB), pull frags to regs
    {
        const size_t qb = (size_t)(b * 64 + qt0) * 8192;
        #pragma unroll
        for (int i = 0; i < 4; ++i) {
            const int p = wv * 4 + i;
            gl2lds16(Qfm + qb + (size_t)p * 512 + lane * 8, &Klds[0][0] + p * 512);
        }
    }
    __syncthreads();
    bf16x8 qf[4];
    {
        const unsigned short* Qt = &Klds[wv >> 2][0];
        #pragma unroll
        for (int c = 0; c < 4; ++c)
            qf[c] = *(const bf16x8*)&Qt[((c * 4 + quad) * 64 + rw + lm) * 8];
    }
    asm volatile("s_waitcnt lgkmcnt(0)" ::: "memory");   // qf secured
    __builtin_amdgcn_s_barrier();

    // prologue: first K/V tile -> buf 0 (overwrites Q: safe)
    {
        const size_t kb = (size_t)(b * 64 + ktb) * 8192;
        #pragma unroll
        for (int i = 0; i < 2; ++i) {
            const int pc = wv * 2 + i;
            gl2lds16(Kfm + kb + pc * 512 + lane * 8, &Klds[0][pc * 512]);
            gl2lds16(Vfm + kb + pc * 512 + lane * 8, &Vlds[0][pc * 512]);
        }
    }

    f32x4 oacc[8];
    #pragma unroll
    for (int oc = 0; oc < 8; ++oc) oacc[oc] = f32x4{0.f, 0.f, 0.f, 0.f};
    f32x4 m4 = f32x4{-INFINITY, -INFINITY, -INFINITY, -INFINITY};
    f32x4 lacc = f32x4{0.f, 0.f, 0.f, 0.f};
    unsigned short* Pw = Plds[wv];
    const short ONE = (short)0x3F80;             // bf16 1.0
    const bf16x8 ONESB = {ONE, ONE, ONE, ONE, ONE, ONE, ONE, ONE};

    for (int kt = ktb; kt < kte; ++kt) {
        const int cu = (kt - ktb) & 1;
        __builtin_amdgcn_s_barrier();    // B1: buf[cu^1] free to overwrite
        if (kt + 1 < kte) {
            const size_t kb = (size_t)(b * 64 + kt + 1) * 8192;
            #pragma unroll
            for (int i = 0; i < 2; ++i) {
                const int pc = wv * 2 + i;
                gl2lds16(Kfm + kb + pc * 512 + lane * 8, &Klds[cu ^ 1][pc * 512]);
                gl2lds16(Vfm + kb + pc * 512 + lane * 8, &Vlds[cu ^ 1][pc * 512]);
            }
            asm volatile("s_waitcnt vmcnt(4)" ::: "memory");  // tile kt done
        } else {
            asm volatile("s_waitcnt vmcnt(0)" ::: "memory");
        }
        __builtin_amdgcn_s_barrier();    // B2: buf[cu] ready
        if (kt > qtw) continue;          // wave's rows fully masked this tile

        const unsigned short* Kc = &Klds[cu][0];
        const unsigned short* Vc = &Vlds[cu][0];

        // S = Q K^T (Q pre-scaled to base-2)
        f32x4 sv[4];
        __builtin_amdgcn_s_setprio(1);
        #pragma unroll
        for (int ct = 0; ct < 4; ++ct) {
            f32x4 a = f32x4{0.f, 0.f, 0.f, 0.f};
            #pragma unroll
            for (int c = 0; c < 4; ++c) {
                bf16x8 kf = *(const bf16x8*)&Kc[((c * 4 + quad) * 64 + ct * 16 + lm) * 8];
                a = mfma16(qf[c], kf, a);
            }
            sv[ct] = a;
        }
        __builtin_amdgcn_s_setprio(0);
        if (kt == qtw) {                 // diagonal tile: mask key > row
            #pragma unroll
            for (int ct = 0; ct < 4; ++ct) {
                const int dg = ct * 16 + lm - rw - quad * 4;
                #pragma unroll
                for (int rr = 0; rr < 4; ++rr)
                    if (dg > rr) sv[ct][rr] = -INFINITY;
            }
        }
        // defer-max online softmax (base 2)
        const f32x4 pmax = vmax4(vmax4(sv[0], sv[1]), vmax4(sv[2], sv[3]));
        const float dm = fmaxf(fmaxf(pmax[0] - m4[0], pmax[1] - m4[1]),
                               fmaxf(pmax[2] - m4[2], pmax[3] - m4[3]));
        if (!__all(dm <= 8.f)) {
            f32x4 rmax = pmax;
            #pragma unroll
            for (int d = 1; d < 16; d <<= 1) {
                f32x4 o;
                #pragma unroll
                for (int e = 0; e < 4; ++e) o[e] = __shfl_xor(rmax[e], d);
                rmax = vmax4(rmax, o);
            }
            const f32x4 mnew = vmax4(m4, rmax);       // finite here (diag row)
            f32x4 alpha;
            #pragma unroll
            for (int e = 0; e < 4; ++e) alpha[e] = __builtin_amdgcn_exp2f(m4[e] - mnew[e]);
            m4 = mnew;
            #pragma unroll
            for (int oc = 0; oc < 8; ++oc) oacc[oc] *= alpha;
            lacc *= alpha;
        }
        #pragma unroll
        for (int ct = 0; ct < 4; ++ct)
            #pragma unroll
            for (int rr = 0; rr < 4; ++rr)
                sv[ct][rr] = __builtin_amdgcn_exp2f(sv[ct][rr] - m4[rr]);
        // P -> wave-private LDS (A-frag layout)
        #pragma unroll
        for (int ct = 0; ct < 4; ++ct) {
            const int cb = ((ct * 2 + (lm >> 3)) * 16 + quad * 4) * 8 + (lm & 7);
            #pragma unroll
            for (int rr = 0; rr < 4; ++rr)
                Pw[cb + rr * 8] = f2bf(sv[ct][rr]);
        }
        // O += P V ; l += P 1  (row-sum via ones-column MFMA)
        __builtin_amdgcn_s_setprio(1);
        #pragma unroll
        for (int s = 0; s < 2; ++s) {
            bf16x8 pf = *(const bf16x8*)&Pw[((s * 4 + quad) * 16 + lm) * 8];
            lacc = mfma16(pf, ONESB, lacc);
            #pragma unroll
            for (int oc = 0; oc < 8; ++oc) {
                bf16x8 vf = *(const bf16x8*)&Vc[((s * 4 + quad) * 128 + oc * 16 + lm) * 8];
                oacc[oc] = mfma16(pf, vf, oacc[oc]);
            }
        }
        __builtin_amdgcn_s_setprio(0);
    }

    // epilogue: per-wave 64-row tile qtw, rows rw..rw+15
    const size_t obw = (size_t)((b * 64 + qtw) * 4 + sp) * 8192;
    const int mlw = ((b * 64 + qtw) * 4 + sp) * 128;
    #pragma unroll
    for (int oc = 0; oc < 8; ++oc) {
        const size_t cb = obw + (size_t)((oc * 2 + (lm >> 3)) * 64
                          + rw + quad * 4) * 8 + (lm & 7);
        #pragma unroll
        for (int rr = 0; rr < 4; ++rr)
            Opart[cb + rr * 8] = f2bf(oacc[oc][rr]);
    }
    if (lm == 0)
        #pragma unroll
        for (int rr = 0; rr < 4; ++rr) {
            const int row = rw + quad * 4 + rr;
            Ml[mlw + row] = m4[rr];
            Ml[mlw + 64 + row] = lacc[rr];
        }
}

// ---------------------------------------------------------------------------
// Output projection: combine(4 splits) + GEMM + bias. grid 512 (1D) x 512 thr.
// aq = bx&255, nh = bx>>8 -> same-aq pair shares XCD (Opart/Ml L2 hits).
// LDS: A 16 KB + W dbuf 2x32 KB = 80 KB -> 2 blocks/CU.
// ---------------------------------------------------------------------------
__global__ __launch_bounds__(512, 2)
void gemm_outf(const unsigned short* __restrict__ Opart, const float* __restrict__ Ml,
               const unsigned short* __restrict__ Wofm, const float* __restrict__ bias,
               float* __restrict__ out)
{
    __shared__ unsigned short Asl[8192];        // 16 KB combined A (16 kc x 64 rows)
    __shared__ unsigned short Wl[2][16384];     // 2 x 32 KB
    const int tid = threadIdx.x;
    const int wv = tid >> 6, lane = tid & 63;
    const int lm = lane & 15, quad = lane >> 4;
    const int aq = blockIdx.x & 255;            // 0..255 : (b*64 + qt)
    const int nt0 = (blockIdx.x >> 8) * 4;      // n-tile base (4 tiles of 128)
    const size_t pbase = (size_t)aq * 4 * 8192;
    const int mlb = aq * 4 * 128;

    auto issueW = [&](int nt, int buf) {
        #pragma unroll
        for (int i = 0; i < 4; ++i) {
            const int p = wv * 4 + i;           // 0..31 pieces of 1 KB
            gl2lds16(Wofm + (size_t)((nt * 2 + (p >> 4)) * 16 + (p & 15)) * 512 + lane * 8,
                     &Wl[buf][p * 512]);
        }
    };
    issueW(nt0, 0);                             // W(nt0) in flight under combine

    // ---- Phase 1: combine 4 splits into Asl ----
    {
        const int r = tid & 63;
        float m[4], l[4];
        #pragma unroll
        for (int s = 0; s < 4; ++s) {
            m[s] = Ml[mlb + s * 128 + r];
            l[s] = Ml[mlb + s * 128 + 64 + r];
        }
        const float M = fmaxf(fmaxf(m[0], m[1]), fmaxf(m[2], m[3]));
        float a[4], den = 0.f;
        #pragma unroll
        for (int s = 0; s < 4; ++s) {
            a[s] = __builtin_amdgcn_exp2f(m[s] - M);
            den += a[s] * l[s];
        }
        const float rsc = 1.f / den;
        #pragma unroll
        for (int h = 0; h < 2; ++h) {
            const int g = tid + h * 512;
            float acc8[8] = {};
            #pragma unroll
            for (int s = 0; s < 4; ++s) {
                bf16x8 x = *(const bf16x8*)&Opart[pbase + (size_t)s * 8192 + (size_t)g * 8];
                #pragma unroll
                for (int e = 0; e < 8; ++e) acc8[e] += a[s] * bf2f((unsigned short)x[e]);
            }
            bf16x8 o;
            #pragma unroll
            for (int e = 0; e < 8; ++e) o[e] = f2bf(acc8[e] * rsc);
            *(bf16x8*)&Asl[g * 8] = o;
        }
    }
    __syncthreads();                            // Asl ready

    // ---- Phase 2: 4 N-tiles, W double-buffered ----
    const int rw4 = (wv & 3) * 16;              // wave rows
    const int tl  = wv >> 2;                    // wave col-half (0/1)
    bf16x8 af[4];
    #pragma unroll
    for (int kt = 0; kt < 4; ++kt)
        af[kt] = *(const bf16x8*)&Asl[((kt * 4 + quad) * 64 + rw4 + lm) * 8];

    for (int it = 0; it < 4; ++it) {
        const int nt = nt0 + it;
        const int buf = it & 1;
        if (it < 3) {
            asm volatile("s_waitcnt vmcnt(4)" ::: "memory");   // W(nt) done
        } else {
            asm volatile("s_waitcnt vmcnt(0)" ::: "memory");
        }
        __builtin_amdgcn_s_barrier();           // W(nt) visible; buf^1 free
        if (it < 3) issueW(nt + 1, buf ^ 1);

        f32x4 acc[4];
        #pragma unroll
        for (int j = 0; j < 4; ++j) acc[j] = f32x4{0.f, 0.f, 0.f, 0.f};
        #pragma unroll
        for (int kt = 0; kt < 4; ++kt)
            #pragma unroll
            for (int j = 0; j < 4; ++j) {
                bf16x8 bfr = *(const bf16x8*)
                    &Wl[buf][((tl * 16 + kt * 4 + quad) * 64 + j * 16 + lm) * 8];
                acc[j] = mfma16(af[kt], bfr, acc[j]);
            }
        #pragma unroll
        for (int j = 0; j < 4; ++j) {
            const int col = nt * 128 + tl * 64 + j * 16 + lm;
            const float bv = bias[col];
            #pragma unroll
            for (int rr = 0; rr < 4; ++rr) {
                const int m = aq * 64 + rw4 + quad * 4 + rr;
                out[(size_t)m * 1024 + col] = acc[j][rr] + bv;
            }
        }
        __builtin_amdgcn_s_barrier();           // done reading Wl[buf]
    }
}

// ---------------------------------------------------------------------------
extern "C" void kernel_launch(void* const* d_in, const int* in_sizes, int n_in,
                              void* d_out, int out_size, void* d_ws, size_t ws_size,
                              hipStream_t stream)
{
    (void)in_sizes; (void)n_in; (void)out_size; (void)ws_size;
    const float* x     = (const float*)d_in[0];
    const float* w_qkv = (const float*)d_in[1];
    const float* w_out = (const float*)d_in[2];
    const float* b_out = (const float*)d_in[3];
    float* out = (float*)d_out;
    unsigned short* ws = (unsigned short*)d_ws;

    const size_t NE = (size_t)16384 * 128;          // 2 097 152
    unsigned short* qfm = ws;                        // 4 MB
    unsigned short* kfm = ws + NE;                   // 4 MB
    unsigned short* wofm = ws + 2 * NE;              // w_out bf16 frag-major
    unsigned short* vfm = ws + 3 * NE;               // 4 MB
    unsigned short* op  = ws + 4 * NE;               // Opart 16.8 MB
    float*          ml  = (float*)(ws + 8 * NE);     // 0.5 MB
    unsigned short* wfm = op;                        // alias: dead before flash

    hipLaunchKernelGGL(wcast_all,   dim3(256),      dim3(256), 0, stream, w_qkv, w_out, wfm, wofm);
    hipLaunchKernelGGL(gemm_qkv,    dim3(768),      dim3(256), 0, stream, x, wfm, qfm, kfm, vfm);
    hipLaunchKernelGGL(flash_attn3, dim3(512),      dim3(512), 0, stream, qfm, kfm, vfm, op, ml);
    hipLaunchKernelGGL(gemm_outf,   dim3(512),      dim3(512), 0, stream, op, ml, wofm, b_out, out);
}

// Round 11
// 174.689 us; speedup vs baseline: 1.0984x; 1.0158x over previous
//
#include <hip/hip_runtime.h>
#include <math.h>

// ---------------------------------------------------------------------------
// bf16-MFMA pipeline v15:
//   flash_attn3 : v12 structure + P-granule XOR swizzle (s ^= s>>2 within
//                 each 16-row chunk) — kills the measured 1.06M bank-conflict
//                 cycles on the P ds_write scatter; read side lm ^= lm>>2.
//   gemm_outf   : restored to round-8 2D grid (best-measured config).
//   wcast_all / gemm_qkv : unchanged.
// Layout: addr(tile,c,r,j) = ((tile*NC + c)*64 + r)*8 + j  (NC = K/8)
// ---------------------------------------------------------------------------

typedef __attribute__((ext_vector_type(8))) short bf16x8;
typedef __attribute__((ext_vector_type(4))) short bf16x4;
typedef __attribute__((ext_vector_type(4))) float f32x4;

#define FA_SCL2 0.12751886525137387f   // 128^-0.5 * log2(e)

__device__ __forceinline__ unsigned short f2bf(float f) {
    __bf16 h = (__bf16)f;                       // native cvt (RNE)
    return __builtin_bit_cast(unsigned short, h);
}
__device__ __forceinline__ float bf2f(unsigned short h) {
    union { unsigned u; float f; } v; v.u = ((unsigned)h) << 16;
    return v.f;
}
__device__ __forceinline__ f32x4 mfma16(bf16x8 a, bf16x8 b, f32x4 c) {
    return __builtin_amdgcn_mfma_f32_16x16x32_bf16(a, b, c, 0, 0, 0);
}
__device__ __forceinline__ void gl2lds16(const void* g, void* l) {
    __builtin_amdgcn_global_load_lds(
        (const __attribute__((address_space(1))) unsigned int*)g,
        (__attribute__((address_space(3))) unsigned int*)l, 16, 0, 0);
}
__device__ __forceinline__ f32x4 vmax4(f32x4 a, f32x4 b) {
    return f32x4{fmaxf(a[0], b[0]), fmaxf(a[1], b[1]),
                 fmaxf(a[2], b[2]), fmaxf(a[3], b[3])};
}

// ---------------------------------------------------------------------------
// Merged weight cast. bx<192: w_qkv fp32[384][1024] -> Wfm frag-major.
// bx>=192: w_out fp32[1024][128] -> Wofm frag-major 64-row tiles.
// grid 256 x 256 thr.
// ---------------------------------------------------------------------------
__global__ __launch_bounds__(256)
void wcast_all(const float* __restrict__ Wq, const float* __restrict__ Wo,
               unsigned short* __restrict__ wfm, unsigned short* __restrict__ wofm)
{
    const int bx = blockIdx.x, tid = threadIdx.x;
    if (bx < 192) {
        const int idx = bx * 256 + tid;               // 49152 granules
        const int kc = idx & 127, r = idx >> 7;
        const float* g = Wq + (size_t)r * 1024 + kc * 8;
        float4 w0 = *(const float4*)g, w1 = *(const float4*)(g + 4);
        bf16x8 p;
        p[0] = (short)f2bf(w0.x); p[1] = (short)f2bf(w0.y);
        p[2] = (short)f2bf(w0.z); p[3] = (short)f2bf(w0.w);
        p[4] = (short)f2bf(w1.x); p[5] = (short)f2bf(w1.y);
        p[6] = (short)f2bf(w1.z); p[7] = (short)f2bf(w1.w);
        *(bf16x8*)&wfm[(size_t)(kc * 384 + r) * 8] = p;
    } else {
        const int idx = (bx - 192) * 256 + tid;       // 16384 granules
        const int c = idx & 15, rg = idx >> 4;        // rg in [0,1024)
        const float* g = Wo + (size_t)rg * 128 + c * 8;
        float4 w0 = *(const float4*)g, w1 = *(const float4*)(g + 4);
        bf16x8 p;
        p[0] = (short)f2bf(w0.x); p[1] = (short)f2bf(w0.y);
        p[2] = (short)f2bf(w0.z); p[3] = (short)f2bf(w0.w);
        p[4] = (short)f2bf(w1.x); p[5] = (short)f2bf(w1.y);
        p[6] = (short)f2bf(w1.z); p[7] = (short)f2bf(w1.w);
        *(bf16x8*)&wofm[((size_t)((rg >> 6) * 16 + c) * 64 + (rg & 63)) * 8] = p;
    }
}

// ---------------------------------------------------------------------------
// Fused QKV projection (unchanged). BM=64, BN=128 section, BK=64.
// grid 768 x 256 thr. V^T folded into epilogue.
// ---------------------------------------------------------------------------
__global__ __launch_bounds__(256, 3)
void gemm_qkv(const float* __restrict__ X, const unsigned short* __restrict__ Wfm,
              unsigned short* __restrict__ qfm, unsigned short* __restrict__ kfm,
              unsigned short* __restrict__ vfm)
{
    __shared__ unsigned short Asl[4096];         // 8 KB: granule(kc, row^kc)
    __shared__ unsigned short Bsl[2][8192];      // 2 x 16 KB: granule(kc, col)
    const int tid = threadIdx.x;
    const int wv = tid >> 6, lane = tid & 63;
    const int lm = lane & 15, quad = lane >> 4;
    const int mt = blockIdx.x & 255;             // M tile (64 rows) == Vfm tile
    const int nt = blockIdx.x >> 8;              // 0=Q, 1=K, 2=V
    const int mb = mt * 64, nb = nt * 128;
    const int wr = wv >> 1, wc = wv & 1;         // wave: rows wr*32, cols wc*64

    const int arow = tid >> 3, af8 = tid & 7;    // arow in [0,32)
    const float* gxr = X + (size_t)(mb + arow) * 1024 + af8 * 8;
    const int sg0 = (af8 * 64 + (arow ^ af8)) * 8;        // swizzled granule
    const int sg1 = sg0 + 32 * 8;                          // (arow+32)^af8

    f32x4 acc[2][4];
    #pragma unroll
    for (int i = 0; i < 2; ++i)
        #pragma unroll
        for (int j = 0; j < 4; ++j) acc[i][j] = f32x4{0.f, 0.f, 0.f, 0.f};

    auto loadA = [&](int it, float4& r0, float4& r1, float4& r2, float4& r3) {
        const float* g = gxr + it * 64;
        r0 = *(const float4*)g;
        r1 = *(const float4*)(g + 4);
        r2 = *(const float4*)(g + 32 * 1024);
        r3 = *(const float4*)(g + 32 * 1024 + 4);
    };
    auto stageA = [&](const float4& r0, const float4& r1,
                      const float4& r2, const float4& r3) {
        bf16x8 p0, p1;
        p0[0] = (short)f2bf(r0.x); p0[1] = (short)f2bf(r0.y);
        p0[2] = (short)f2bf(r0.z); p0[3] = (short)f2bf(r0.w);
        p0[4] = (short)f2bf(r1.x); p0[5] = (short)f2bf(r1.y);
        p0[6] = (short)f2bf(r1.z); p0[7] = (short)f2bf(r1.w);
        *(bf16x8*)&Asl[sg0] = p0;
        p1[0] = (short)f2bf(r2.x); p1[1] = (short)f2bf(r2.y);
        p1[2] = (short)f2bf(r2.z); p1[3] = (short)f2bf(r2.w);
        p1[4] = (short)f2bf(r3.x); p1[5] = (short)f2bf(r3.y);
        p1[6] = (short)f2bf(r3.z); p1[7] = (short)f2bf(r3.w);
        *(bf16x8*)&Asl[sg1] = p1;
    };
    auto issueB = [&](int it, int buf) {
        #pragma unroll
        for (int i = 0; i < 4; ++i) {
            const int p = wv * 4 + i;
            const int kc = p >> 1, colh = (p & 1) * 64;
            gl2lds16(Wfm + ((size_t)(it * 8 + kc) * 384 + nb + colh + lane) * 8,
                     &Bsl[buf][(kc * 128 + colh) * 8]);
        }
    };

    float4 a0, a1, a2, a3, b0, b1, b2, b3;
    loadA(0, a0, a1, a2, a3);
    issueB(0, 0);
    loadA(1, b0, b1, b2, b3);

    auto step = [&](const int i, float4& r0, float4& r1, float4& r2, float4& r3) {
        __builtin_amdgcn_s_barrier();            // B1: Asl + Bsl[(i+1)&1] free
        stageA(r0, r1, r2, r3);                  // implicit vmcnt wait for A(i)
        if (i < 15) issueB(i + 1, (i + 1) & 1);
        if (i < 14) {
            loadA(i + 2, r0, r1, r2, r3);        // 2-iter slack
            asm volatile("s_waitcnt vmcnt(12) lgkmcnt(0)" ::: "memory"); // B(i) done
        } else if (i == 14) {
            asm volatile("s_waitcnt vmcnt(8) lgkmcnt(0)" ::: "memory");
        } else {
            asm volatile("s_waitcnt vmcnt(0) lgkmcnt(0)" ::: "memory");
        }
        __builtin_amdgcn_s_barrier();            // B2: tile i ready
        const unsigned short* Bc = Bsl[i & 1];
        bf16x8 af[2][2], bfr[2][4];
        #pragma unroll
        for (int s = 0; s < 2; ++s) {
            const int kc = s * 4 + quad;
            #pragma unroll
            for (int ii = 0; ii < 2; ++ii)
                af[s][ii] = *(const bf16x8*)
                    &Asl[(kc * 64 + ((wr * 32 + ii * 16 + lm) ^ kc)) * 8];
            #pragma unroll
            for (int j = 0; j < 4; ++j)
                bfr[s][j] = *(const bf16x8*)&Bc[(kc * 128 + wc * 64 + j * 16 + lm) * 8];
        }
        #pragma unroll
        for (int s = 0; s < 2; ++s)
            #pragma unroll
            for (int ii = 0; ii < 2; ++ii)
                #pragma unroll
                for (int j = 0; j < 4; ++j)
                    acc[ii][j] = mfma16(af[s][ii], bfr[s][j], acc[ii][j]);
    };

    for (int p = 0; p < 8; ++p) {
        step(2 * p,     a0, a1, a2, a3);
        step(2 * p + 1, b0, b1, b2, b3);
    }

    if (nt == 2) {
        // V: transpose in LDS (T[d][k], stride 72; aliases dead Bsl) and
        // write Vfm tile mt directly.
        unsigned short* T = &Bsl[0][0];          // 128*72*2 = 18.4 KB < 32 KB
        __syncthreads();
        #pragma unroll
        for (int ii = 0; ii < 2; ++ii)
            #pragma unroll
            for (int j = 0; j < 4; ++j) {
                const int d = wc * 64 + j * 16 + lm;
                const int k0 = wr * 32 + ii * 16 + quad * 4;
                bf16x4 v;
                v[0] = (short)f2bf(acc[ii][j][0]);
                v[1] = (short)f2bf(acc[ii][j][1]);
                v[2] = (short)f2bf(acc[ii][j][2]);
                v[3] = (short)f2bf(acc[ii][j][3]);
                *(bf16x4*)&T[d * 72 + k0] = v;
            }
        __syncthreads();
        unsigned short* dst = vfm + (size_t)mt * 8192;
        #pragma unroll
        for (int t = 0; t < 4; ++t) {
            const int g = tid + t * 256;         // granule: d = g&127, c = g>>7
            const int d = g & 127, c = g >> 7;
            bf16x8 x = *(const bf16x8*)&T[d * 72 + c * 8];
            *(bf16x8*)(dst + (size_t)(c * 128 + d) * 8) = x;   // coalesced
        }
    } else {                                    // Q (scaled) / K: frag-major
        unsigned short* dst = nt ? kfm : qfm;
        const float scl = nt ? 1.f : FA_SCL2;
        #pragma unroll
        for (int ii = 0; ii < 2; ++ii)
            #pragma unroll
            for (int j = 0; j < 4; ++j) {
                const int ncol = wc * 64 + j * 16 + lm;
                const size_t cb = ((size_t)mt * 16 + (ncol >> 3)) * 512 + (ncol & 7);
                #pragma unroll
                for (int r = 0; r < 4; ++r)
                    dst[cb + (size_t)(wr * 32 + ii * 16 + quad * 4 + r) * 8]
                        = f2bf(acc[ii][j][r] * scl);
            }
    }
}

// ---------------------------------------------------------------------------
// Flash attention v15: v12 + P-granule XOR swizzle (bank-conflict fix).
// 512 thr, Br=128, balanced, ones-col MFMA, defer-max, masked-tile skip.
// ---------------------------------------------------------------------------
__global__ __launch_bounds__(512, 4)
void flash_attn3(const unsigned short* __restrict__ Qfm, const unsigned short* __restrict__ Kfm,
                 const unsigned short* __restrict__ Vfm,
                 unsigned short* __restrict__ Opart, float* __restrict__ Ml)
{
    __shared__ unsigned short Klds[2][8192];    // 2 x 16 KB (Q stages both)
    __shared__ unsigned short Vlds[2][8192];    // 2 x 16 KB
    __shared__ unsigned short Plds[8][1024];    // per-wave P (A-frag), 16 KB

    const int tid = threadIdx.x;
    const int wv = tid >> 6, lane = tid & 63;
    const int lm = lane & 15, quad = lane >> 4;

    const int bx = blockIdx.x;
    const int xcd = bx & 7;
    const int b   = xcd >> 1;                    // batch on XCD pair {2b,2b+1}
    const int r   = (bx >> 3) * 2 + (xcd & 1);   // [0,128) per batch
    const int sp  = r & 3;
    const int Qi  = (r < 64) ? (16 + (r >> 2)) : (15 - ((r - 64) >> 2));
    const int n   = 2 * Qi + 2;                  // key tiles for this Q-block
    const int cnt = (n >> 2) + ((sp < (n & 3)) ? 1 : 0);
    const int ktb = sp * (n >> 2) + ((sp < (n & 3)) ? sp : (n & 3));
    const int kte = ktb + cnt;
    const int qtw = 2 * Qi + (wv >> 2);          // wave's 64-row q-tile
    const int rw  = (wv & 3) * 16;               // wave's rows inside the tile

    const int qt0 = 2 * Qi;
    const size_t ob0 = (size_t)((b * 64 + qt0) * 4 + sp) * 8192;
    const size_t ob1 = ob0 + 4 * 8192;
    const int mlb0 = ((b * 64 + qt0) * 4 + sp) * 128, mlb1 = mlb0 + 512;

    if (cnt == 0) {                      // neutral partial (both tiles)
        bf16x8 z = {0, 0, 0, 0, 0, 0, 0, 0};
        #pragma unroll
        for (int t = 0; t < 2; ++t) {
            *(bf16x8*)&Opart[ob0 + (size_t)(tid + t * 512) * 8] = z;
            *(bf16x8*)&Opart[ob1 + (size_t)(tid + t * 512) * 8] = z;
        }
        if (tid < 64) { Ml[mlb0 + tid] = -INFINITY; Ml[mlb1 + tid] = -INFINITY; }
        else if (tid < 128) { Ml[mlb0 + tid] = 0.f; Ml[mlb1 + tid] = 0.f; }
        return;
    }

    // stage both Q tiles (32 KB), pull frags to regs
    {
        const size_t qb = (size_t)(b * 64 + qt0) * 8192;
        #pragma unroll
        for (int i = 0; i < 4; ++i) {
            const int p = wv * 4 + i;
            gl2lds16(Qfm + qb + (size_t)p * 512 + lane * 8, &Klds[0][0] + p * 512);
        }
    }
    __syncthreads();
    bf16x8 qf[4];
    {
        const unsigned short* Qt = &Klds[wv >> 2][0];
        #pragma unroll
        for (int c = 0; c < 4; ++c)
            qf[c] = *(const bf16x8*)&Qt[((c * 4 + quad) * 64 + rw + lm) * 8];
    }
    asm volatile("s_waitcnt lgkmcnt(0)" ::: "memory");   // qf secured
    __builtin_amdgcn_s_barrier();

    // prologue: first K/V tile -> buf 0 (overwrites Q: safe)
    {
        const size_t kb = (size_t)(b * 64 + ktb) * 8192;
        #pragma unroll
        for (int i = 0; i < 2; ++i) {
            const int pc = wv * 2 + i;
            gl2lds16(Kfm + kb + pc * 512 + lane * 8, &Klds[0][pc * 512]);
            gl2lds16(Vfm + kb + pc * 512 + lane * 8, &Vlds[0][pc * 512]);
        }
    }

    f32x4 oacc[8];
    #pragma unroll
    for (int oc = 0; oc < 8; ++oc) oacc[oc] = f32x4{0.f, 0.f, 0.f, 0.f};
    f32x4 m4 = f32x4{-INFINITY, -INFINITY, -INFINITY, -INFINITY};
    f32x4 lacc = f32x4{0.f, 0.f, 0.f, 0.f};
    unsigned short* Pw = Plds[wv];
    const short ONE = (short)0x3F80;             // bf16 1.0
    const bf16x8 ONESB = {ONE, ONE, ONE, ONE, ONE, ONE, ONE, ONE};
    const int lmx = lm ^ (lm >> 2);              // P read-side sub-row swizzle

    for (int kt = ktb; kt < kte; ++kt) {
        const int cu = (kt - ktb) & 1;
        __builtin_amdgcn_s_barrier();    // B1: buf[cu^1] free to overwrite
        if (kt + 1 < kte) {
            const size_t kb = (size_t)(b * 64 + kt + 1) * 8192;
            #pragma unroll
            for (int i = 0; i < 2; ++i) {
                const int pc = wv * 2 + i;
                gl2lds16(Kfm + kb + pc * 512 + lane * 8, &Klds[cu ^ 1][pc * 512]);
                gl2lds16(Vfm + kb + pc * 512 + lane * 8, &Vlds[cu ^ 1][pc * 512]);
            }
            asm volatile("s_waitcnt vmcnt(4)" ::: "memory");  // tile kt done
        } else {
            asm volatile("s_waitcnt vmcnt(0)" ::: "memory");
        }
        __builtin_amdgcn_s_barrier();    // B2: buf[cu] ready
        if (kt > qtw) continue;          // wave's rows fully masked this tile

        const unsigned short* Kc = &Klds[cu][0];
        const unsigned short* Vc = &Vlds[cu][0];

        // S = Q K^T (Q pre-scaled to base-2)
        f32x4 sv[4];
        __builtin_amdgcn_s_setprio(1);
        #pragma unroll
        for (int ct = 0; ct < 4; ++ct) {
            f32x4 a = f32x4{0.f, 0.f, 0.f, 0.f};
            #pragma unroll
            for (int c = 0; c < 4; ++c) {
                bf16x8 kf = *(const bf16x8*)&Kc[((c * 4 + quad) * 64 + ct * 16 + lm) * 8];
                a = mfma16(qf[c], kf, a);
            }
            sv[ct] = a;
        }
        __builtin_amdgcn_s_setprio(0);
        if (kt == qtw) {                 // diagonal tile: mask key > row
            #pragma unroll
            for (int ct = 0; ct < 4; ++ct) {
                const int dg = ct * 16 + lm - rw - quad * 4;
                #pragma unroll
                for (int rr = 0; rr < 4; ++rr)
                    if (dg > rr) sv[ct][rr] = -INFINITY;
            }
        }
        // defer-max online softmax (base 2)
        const f32x4 pmax = vmax4(vmax4(sv[0], sv[1]), vmax4(sv[2], sv[3]));
        const float dm = fmaxf(fmaxf(pmax[0] - m4[0], pmax[1] - m4[1]),
                               fmaxf(pmax[2] - m4[2], pmax[3] - m4[3]));
        if (!__all(dm <= 8.f)) {
            f32x4 rmax = pmax;
            #pragma unroll
            for (int d = 1; d < 16; d <<= 1) {
                f32x4 o;
                #pragma unroll
                for (int e = 0; e < 4; ++e) o[e] = __shfl_xor(rmax[e], d);
                rmax = vmax4(rmax, o);
            }
            const f32x4 mnew = vmax4(m4, rmax);       // finite here (diag row)
            f32x4 alpha;
            #pragma unroll
            for (int e = 0; e < 4; ++e) alpha[e] = __builtin_amdgcn_exp2f(m4[e] - mnew[e]);
            m4 = mnew;
            #pragma unroll
            for (int oc = 0; oc < 8; ++oc) oacc[oc] *= alpha;
            lacc *= alpha;
        }
        #pragma unroll
        for (int ct = 0; ct < 4; ++ct)
            #pragma unroll
            for (int rr = 0; rr < 4; ++rr)
                sv[ct][rr] = __builtin_amdgcn_exp2f(sv[ct][rr] - m4[rr]);
        // P -> wave-private LDS (A-frag layout, sub-row XOR swizzle s^=s>>2:
        // write-wave rows land in 4 distinct banks-mod-8 instead of 2)
        #pragma unroll
        for (int ct = 0; ct < 4; ++ct) {
            const int chunk = ct * 2 + (lm >> 3);
            #pragma unroll
            for (int rr = 0; rr < 4; ++rr) {
                const int s = quad * 4 + rr;
                const int sx = s ^ (s >> 2);
                Pw[(chunk * 16 + sx) * 8 + (lm & 7)] = f2bf(sv[ct][rr]);
            }
        }
        // O += P V ; l += P 1  (row-sum via ones-column MFMA)
        __builtin_amdgcn_s_setprio(1);
        #pragma unroll
        for (int s = 0; s < 2; ++s) {
            bf16x8 pf = *(const bf16x8*)&Pw[((s * 4 + quad) * 16 + lmx) * 8];
            lacc = mfma16(pf, ONESB, lacc);
            #pragma unroll
            for (int oc = 0; oc < 8; ++oc) {
                bf16x8 vf = *(const bf16x8*)&Vc[((s * 4 + quad) * 128 + oc * 16 + lm) * 8];
                oacc[oc] = mfma16(pf, vf, oacc[oc]);
            }
        }
        __builtin_amdgcn_s_setprio(0);
    }

    // epilogue: per-wave 64-row tile qtw, rows rw..rw+15
    const size_t obw = (size_t)((b * 64 + qtw) * 4 + sp) * 8192;
    const int mlw = ((b * 64 + qtw) * 4 + sp) * 128;
    #pragma unroll
    for (int oc = 0; oc < 8; ++oc) {
        const size_t cb = obw + (size_t)((oc * 2 + (lm >> 3)) * 64
                          + rw + quad * 4) * 8 + (lm & 7);
        #pragma unroll
        for (int rr = 0; rr < 4; ++rr)
            Opart[cb + rr * 8] = f2bf(oacc[oc][rr]);
    }
    if (lm == 0)
        #pragma unroll
        for (int rr = 0; rr < 4; ++rr) {
            const int row = rw + quad * 4 + rr;
            Ml[mlw + row] = m4[rr];
            Ml[mlw + 64 + row] = lacc[rr];
        }
}

// ---------------------------------------------------------------------------
// Output projection (round-8 config): combine(4 splits) + GEMM + bias.
// grid (256 aq, 2 nh) x 512 thr. LDS: A 16 KB + W dbuf 2x32 KB = 80 KB.
// ---------------------------------------------------------------------------
__global__ __launch_bounds__(512, 2)
void gemm_outf(const unsigned short* __restrict__ Opart, const float* __restrict__ Ml,
               const unsigned short* __restrict__ Wofm, const float* __restrict__ bias,
               float* __restrict__ out)
{
    __shared__ unsigned short Asl[8192];        // 16 KB combined A (16 kc x 64 rows)
    __shared__ unsigned short Wl[2][16384];     // 2 x 32 KB
    const int tid = threadIdx.x;
    const int wv = tid >> 6, lane = tid & 63;
    const int lm = lane & 15, quad = lane >> 4;
    const int aq = blockIdx.x;                  // 0..255 : (b*64 + qt)
    const int nt0 = blockIdx.y * 4;             // n-tile base (4 tiles of 128)
    const size_t pbase = (size_t)aq * 4 * 8192;
    const int mlb = aq * 4 * 128;

    auto issueW = [&](int nt, int buf) {
        #pragma unroll
        for (int i = 0; i < 4; ++i) {
            const int p = wv * 4 + i;           // 0..31 pieces of 1 KB
            gl2lds16(Wofm + (size_t)((nt * 2 + (p >> 4)) * 16 + (p & 15)) * 512 + lane * 8,
                     &Wl[buf][p * 512]);
        }
    };
    issueW(nt0, 0);                             // W(nt0) in flight under combine

    // ---- Phase 1: combine 4 splits into Asl ----
    {
        const int r = tid & 63;
        float m[4], l[4];
        #pragma unroll
        for (int s = 0; s < 4; ++s) {
            m[s] = Ml[mlb + s * 128 + r];
            l[s] = Ml[mlb + s * 128 + 64 + r];
        }
        const float M = fmaxf(fmaxf(m[0], m[1]), fmaxf(m[2], m[3]));
        float a[4], den = 0.f;
        #pragma unroll
        for (int s = 0; s < 4; ++s) {
            a[s] = __builtin_amdgcn_exp2f(m[s] - M);
            den += a[s] * l[s];
        }
        const float rsc = 1.f / den;
        #pragma unroll
        for (int h = 0; h < 2; ++h) {
            const int g = tid + h * 512;
            float acc8[8] = {};
            #pragma unroll
            for (int s = 0; s < 4; ++s) {
                bf16x8 x = *(const bf16x8*)&Opart[pbase + (size_t)s * 8192 + (size_t)g * 8];
                #pragma unroll
                for (int e = 0; e < 8; ++e) acc8[e] += a[s] * bf2f((unsigned short)x[e]);
            }
            bf16x8 o;
            #pragma unroll
            for (int e = 0; e < 8; ++e) o[e] = f2bf(acc8[e] * rsc);
            *(bf16x8*)&Asl[g * 8] = o;
        }
    }
    __syncthreads();                            // Asl ready

    // ---- Phase 2: 4 N-tiles, W double-buffered ----
    const int rw4 = (wv & 3) * 16;              // wave rows
    const int tl  = wv >> 2;                    // wave col-half (0/1)
    bf16x8 af[4];
    #pragma unroll
    for (int kt = 0; kt < 4; ++kt)
        af[kt] = *(const bf16x8*)&Asl[((kt * 4 + quad) * 64 + rw4 + lm) * 8];

    for (int it = 0; it < 4; ++it) {
        const int nt = nt0 + it;
        const int buf = it & 1;
        if (it < 3) {
            asm volatile("s_waitcnt vmcnt(4)" ::: "memory");   // W(nt) done
        } else {
            asm volatile("s_waitcnt vmcnt(0)" ::: "memory");
        }
        __builtin_amdgcn_s_barrier();           // W(nt) visible; buf^1 free
        if (it < 3) issueW(nt + 1, buf ^ 1);

        f32x4 acc[4];
        #pragma unroll
        for (int j = 0; j < 4; ++j) acc[j] = f32x4{0.f, 0.f, 0.f, 0.f};
        #pragma unroll
        for (int kt = 0; kt < 4; ++kt)
            #pragma unroll
            for (int j = 0; j < 4; ++j) {
                bf16x8 bfr = *(const bf16x8*)
                    &Wl[buf][((tl * 16 + kt * 4 + quad) * 64 + j * 16 + lm) * 8];
                acc[j] = mfma16(af[kt], bfr, acc[j]);
            }
        #pragma unroll
        for (int j = 0; j < 4; ++j) {
            const int col = nt * 128 + tl * 64 + j * 16 + lm;
            const float bv = bias[col];
            #pragma unroll
            for (int rr = 0; rr < 4; ++rr) {
                const int m = aq * 64 + rw4 + quad * 4 + rr;
                out[(size_t)m * 1024 + col] = acc[j][rr] + bv;
            }
        }
        __builtin_amdgcn_s_barrier();           // done reading Wl[buf]
    }
}

// ---------------------------------------------------------------------------
extern "C" void kernel_launch(void* const* d_in, const int* in_sizes, int n_in,
                              void* d_out, int out_size, void* d_ws, size_t ws_size,
                              hipStream_t stream)
{
    (void)in_sizes; (void)n_in; (void)out_size; (void)ws_size;
    const float* x     = (const float*)d_in[0];
    const float* w_qkv = (const float*)d_in[1];
    const float* w_out = (const float*)d_in[2];
    const float* b_out = (const float*)d_in[3];
    float* out = (float*)d_out;
    unsigned short* ws = (unsigned short*)d_ws;

    const size_t NE = (size_t)16384 * 128;          // 2 097 152
    unsigned short* qfm = ws;                        // 4 MB
    unsigned short* kfm = ws + NE;                   // 4 MB
    unsigned short* wofm = ws + 2 * NE;              // w_out bf16 frag-major
    unsigned short* vfm = ws + 3 * NE;               // 4 MB
    unsigned short* op  = ws + 4 * NE;               // Opart 16.8 MB
    float*          ml  = (float*)(ws + 8 * NE);     // 0.5 MB
    unsigned short* wfm = op;                        // alias: dead before flash

    hipLaunchKernelGGL(wcast_all,   dim3(256),      dim3(256), 0, stream, w_qkv, w_out, wfm, wofm);
    hipLaunchKernelGGL(gemm_qkv,    dim3(768),      dim3(256), 0, stream, x, wfm, qfm, kfm, vfm);
    hipLaunchKernelGGL(flash_attn3, dim3(512),      dim3(512), 0, stream, qfm, kfm, vfm, op, ml);
    hipLaunchKernelGGL(gemm_outf,   dim3(256, 2),   dim3(512), 0, stream, op, ml, wofm, b_out, out);
}